// Round 5
// baseline (247.752 us; speedup 1.0000x reference)
//
#include <hip/hip_runtime.h>

// FourierFeatureMLP fused kernel for MI355X (gfx950). Round 10.
//
// vs round 9 (184 us; MfmaUtil 34, VALUBusy 46, VGPR 128 = at the
// 2-waves/SIMD register cliff, occupancy locked): per-SIMD budget
// matrix 159k + VALU 56k + trans 66k of 442k wall -> ~160k cyc stall.
// Chief suspect: per-slice bias float4 loads issued ~10 instrs before
// use (LLVM won't hoist at this reg pressure) -> ~150 cyc exposed x 4
// slices x 32 chunks. Fixes:
//   * 2-slot bias ring: slice kt uses bR[kt&1], loads slice kt+1's
//     bias; kt=3 loads NEXT chunk's slice-0 bias (bNxt ptr). +8 VGPR.
//   * kt order: [A prefetch] -> [epilogue slice] -> [MFMA x8] so slice
//     VALU/trans covers the vmcnt window.
//   * T5 s_setprio(1/0) around the MFMA cluster (2 barrier-free waves
//     per SIMD at drifted phases = the role-diversity regime).
//
// Layouts (MFMA 16x16x32, learn_hip-verified):
//   A: lane holds A[m=lane&15][k=quad*8+j]   (W fragment)
//   B: lane holds B[k=quad*8+j][n=lane&15]   (h fragment, n = point)
//   D: n(point)=lane&15, m(unit)=quad*4+reg
// Weights fragment-major: frag = ((layer*4+c)*4+mt)*8+kt, 1 KB each,
// addr = frag*1024 + lane*16 -> fully-coalesced b128 loads.
// Epilogue frag mapping: CE -> next-layer h frags {2*CE, 2*CE+1}.

#define HDIM   256
#define NLAYER 8
#define PTSW   32
#define NTHR   256
#define TILE_N 128
#define WHALVES (NLAYER * HDIM * HDIM)

typedef __attribute__((ext_vector_type(8))) _Float16 half8;
typedef __attribute__((ext_vector_type(4))) _Float16 half4;
typedef __attribute__((ext_vector_type(2))) _Float16 half2;
typedef __attribute__((ext_vector_type(4))) float float4v;

__device__ __forceinline__ half2 pk2(float a, float b) {
    return __builtin_bit_cast(half2, __builtin_amdgcn_cvt_pkrtz(a, b));
}

// tanh(acc + b) with pre-scaled bias bK = b * 2/ln2:
// t = acc*K + bK; z = 2^t; r = 1/(1+z); tanh = 1 - 2r. Saturation-safe.
#define TANH_K 2.885390081777927f
__device__ __forceinline__ float fast_tanh_fused(float acc, float bK) {
    float z = __builtin_amdgcn_exp2f(fmaf(acc, TANH_K, bK));
    float r = __builtin_amdgcn_rcpf(z + 1.0f);
    return fmaf(-2.0f, r, 1.0f);
}

// ---- pre-pass: fp32 -> fp16 weights, permuted to FRAGMENT-major order,
// plus pre-scaled f32 bias table bK[layer*256+u] at halfs offset WHALVES.
__global__ void convert_w_kernel(const float* __restrict__ W_in,
                                 const float* __restrict__ W_h,
                                 const float* __restrict__ b_in,
                                 const float* __restrict__ b_h,
                                 _Float16* __restrict__ dst)
{
    const int i = blockIdx.x * blockDim.x + threadIdx.x;   // 0 .. WHALVES-1
    const int j     = i & 7;
    const int lane  = (i >> 3) & 63;
    const int frag  = i >> 9;
    const int kt    = frag & 7;
    const int mt    = (frag >> 3) & 3;
    const int c     = (frag >> 5) & 3;
    const int layer = frag >> 7;
    const int u = c * 64 + mt * 16 + (lane & 15);
    const int k = kt * 32 + (lane >> 4) * 8 + j;
    const float v = (layer == 0) ? W_in[u * HDIM + k]
                                 : W_h[((layer - 1) * HDIM + u) * HDIM + k];
    dst[i] = (_Float16)v;

    if (i < NLAYER * HDIM) {                               // bias table
        float* bk = (float*)(dst + WHALVES);
        const int l = i >> 8, uu = i & 255;
        const float b = (l == 0) ? b_in[uu] : b_h[(l - 1) * HDIM + uu];
        bk[i] = b * TANH_K;
    }
}

// One chunk's K-loop (8 kt, 8 MFMA each) with the PREVIOUS chunk's (CE)
// epilogue interleaved BEFORE each kt's MFMA cluster: tanh slices at
// kt=0..3 (bias from the 2-slot ring bR), repack ds_reads at kt=4..5.
// bNxt = &bias_cur_layer[C*64 + quad*4] primes next chunk's slice 0.
// CE==-1: no epilogue (first chunk of layer 0); still primes bR at kt=3.
template<int C, int CE>
__device__ __forceinline__ void chunk_step(const _Float16* __restrict__ wl,
                                           const float* __restrict__ blE,
                                           const float* __restrict__ bNxt,
                                           float4 (&bR)[2],
                                           _Float16* __restrict__ ldsE,
                                           const int laneM, const int quad,
                                           const half8 (&hin)[2][8],
                                           half8 (&hdst)[2][8],
                                           float4v (&acc)[4][2],
                                           float4v (&accP)[4][2],
                                           half8 (&A)[2][4])
{
    #pragma unroll
    for (int mt = 0; mt < 4; ++mt)
        #pragma unroll
        for (int nt = 0; nt < 2; ++nt)
            acc[mt][nt] = (float4v){0.f, 0.f, 0.f, 0.f};

    #pragma unroll
    for (int kt = 0; kt < 8; ++kt) {
        const int idx = C * 8 + kt;
        // 1-ahead weight prefetch into the opposite ring slot
        if (idx + 1 < 32) {
            const int c2 = (idx + 1) >> 3, k2 = (idx + 1) & 7;
            #pragma unroll
            for (int mt = 0; mt < 4; ++mt)
                A[(idx + 1) & 1][mt] =
                    *(const half8*)&wl[(c2 * 32 + mt * 8 + k2) * 512];
        }

        // ---- epilogue work for chunk CE, BEFORE this kt's MFMAs ----
        if constexpr (CE >= 0) {
            if (kt < 4) {                       // tanh slice mt = kt
                const int mt = kt;
                const float4 b4 = bR[kt & 1];
                if (kt < 3)                     // prefetch next slice's bias
                    bR[(kt + 1) & 1] =
                        *(const float4*)&blE[CE * 64 + (kt + 1) * 16 + quad * 4];
                const int c8 = mt * 2 + (quad >> 1);
                #pragma unroll
                for (int nt = 0; nt < 2; ++nt) {
                    const int row = nt * 16 + laneM;
                    const float v0 = fast_tanh_fused(accP[mt][nt].x, b4.x);
                    const float v1 = fast_tanh_fused(accP[mt][nt].y, b4.y);
                    const float v2 = fast_tanh_fused(accP[mt][nt].z, b4.z);
                    const float v3 = fast_tanh_fused(accP[mt][nt].w, b4.w);
                    const half2 lo = pk2(v0, v1);
                    const half2 hi = pk2(v2, v3);
                    half4 pkv;
                    pkv.x = lo.x; pkv.y = lo.y; pkv.z = hi.x; pkv.w = hi.y;
                    *(half4*)&ldsE[row * 64 + ((c8 ^ (row & 7)) << 3) + (quad & 1) * 4] = pkv;
                }
            } else if (kt < 6) {                // repack reads kp = kt-4
                const int kp = kt - 4;
                #pragma unroll
                for (int nt = 0; nt < 2; ++nt) {
                    const int row = nt * 16 + laneM;
                    const int c8r = (kp * 4 + quad) ^ (row & 7);
                    hdst[nt][CE * 2 + kp] =
                        *(const half8*)&ldsE[row * 64 + (c8r << 3)];
                }
            }
        }
        if (kt == 3)                            // prime next chunk's slice 0
            bR[0] = *(const float4*)bNxt;

        // ---- MFMA cluster (T5 priority boost) ----
        __builtin_amdgcn_s_setprio(1);
        #pragma unroll
        for (int mt = 0; mt < 4; ++mt)
            #pragma unroll
            for (int nt = 0; nt < 2; ++nt)
                acc[mt][nt] = __builtin_amdgcn_mfma_f32_16x16x32_f16(
                    A[idx & 1][mt], hin[nt][kt], acc[mt][nt], 0, 0, 0);
        __builtin_amdgcn_s_setprio(0);
    }
}

// Standalone drain of the final layer's chunk 3 (CE=3); continues the ring.
__device__ __forceinline__ void tail_epilogue(const float* __restrict__ blE,
                                              float4 (&bR)[2],
                                              _Float16* __restrict__ ldsE,
                                              const int laneM, const int quad,
                                              float4v (&accP)[4][2],
                                              half8 (&hdst)[2][8])
{
    #pragma unroll
    for (int mt = 0; mt < 4; ++mt) {
        const float4 b4 = bR[mt & 1];
        if (mt < 3)
            bR[(mt + 1) & 1] =
                *(const float4*)&blE[3 * 64 + (mt + 1) * 16 + quad * 4];
        const int c8 = mt * 2 + (quad >> 1);
        #pragma unroll
        for (int nt = 0; nt < 2; ++nt) {
            const int row = nt * 16 + laneM;
            const float v0 = fast_tanh_fused(accP[mt][nt].x, b4.x);
            const float v1 = fast_tanh_fused(accP[mt][nt].y, b4.y);
            const float v2 = fast_tanh_fused(accP[mt][nt].z, b4.z);
            const float v3 = fast_tanh_fused(accP[mt][nt].w, b4.w);
            const half2 lo = pk2(v0, v1);
            const half2 hi = pk2(v2, v3);
            half4 pkv;
            pkv.x = lo.x; pkv.y = lo.y; pkv.z = hi.x; pkv.w = hi.y;
            *(half4*)&ldsE[row * 64 + ((c8 ^ (row & 7)) << 3) + (quad & 1) * 4] = pkv;
        }
    }
    #pragma unroll
    for (int kp = 0; kp < 2; ++kp)
        #pragma unroll
        for (int nt = 0; nt < 2; ++nt) {
            const int row = nt * 16 + laneM;
            const int c8r = (kp * 4 + quad) ^ (row & 7);
            hdst[nt][6 + kp] = *(const half8*)&ldsE[row * 64 + (c8r << 3)];
        }
}

__device__ __forceinline__ float dot8(const half8 h, const float4 wa, const float4 wb) {
    return (float)h[0]*wa.x + (float)h[1]*wa.y + (float)h[2]*wa.z + (float)h[3]*wa.w
         + (float)h[4]*wb.x + (float)h[5]*wb.y + (float)h[6]*wb.z + (float)h[7]*wb.w;
}

__global__ __launch_bounds__(NTHR, 2)
void ffmlp_kernel(const float* __restrict__ tx,
                  const float* __restrict__ Bf,
                  const _Float16* __restrict__ Wall,
                  const float* __restrict__ W_out,
                  const float* __restrict__ b_out,
                  float* __restrict__ out)
{
    // 4 waves x 2 chunk-parity buffers x (32 pts x 64 units) fp16 = 32 KB
    __shared__ __align__(16) _Float16 lbuf[4][2][PTSW * 64];

    const int tid   = threadIdx.x;
    const int wave  = tid >> 6;
    const int lane  = tid & 63;
    const int laneM = lane & 15;
    const int quad  = lane >> 4;
    const int qd4   = quad * 4;
    const int p0    = blockIdx.x * TILE_N + wave * PTSW;

    const float* bK = (const float*)(Wall + WHALVES);

    half8 h0[2][8], h1[2][8];

    // -------- stage 1: Fourier features directly into B-frag registers ----
    // k = kq*32 + quad*8 + j ; kq 0..3 -> sin(f=k), kq+4 -> cos(f=k).
    // sin(2*pi*r) = v_sin(fract(r)) : argument in revolutions.
    {
        const float2* txv = (const float2*)tx;
        const float2* Bv  = (const float2*)Bf;
        #pragma unroll
        for (int nt = 0; nt < 2; ++nt) {
            const float2 t = txv[p0 + nt * 16 + laneM];
            #pragma unroll
            for (int kq = 0; kq < 4; ++kq) {
                const int f0 = kq * 32 + quad * 8;
                half8 s8, c8v;
                #pragma unroll
                for (int jj = 0; jj < 8; jj += 2) {
                    const float2 bA = Bv[f0 + jj];
                    const float2 bB = Bv[f0 + jj + 1];
                    const float r0 = __builtin_amdgcn_fractf(t.x * bA.x + t.y * bA.y);
                    const float r1 = __builtin_amdgcn_fractf(t.x * bB.x + t.y * bB.y);
                    const half2 sp = pk2(__builtin_amdgcn_sinf(r0), __builtin_amdgcn_sinf(r1));
                    const half2 cp = pk2(__builtin_amdgcn_cosf(r0), __builtin_amdgcn_cosf(r1));
                    s8[jj] = sp.x;  s8[jj + 1] = sp.y;
                    c8v[jj] = cp.x; c8v[jj + 1] = cp.y;
                }
                h0[nt][kq]     = s8;
                h0[nt][kq + 4] = c8v;
            }
        }
    }

    // -------- stage 2: 8 dense layers, wave-local, NO barriers,
    //          prev-chunk epilogue pipelined into current chunk's K-loop --
    _Float16* __restrict__ lds0 = &lbuf[wave][0][0];
    _Float16* __restrict__ lds1 = &lbuf[wave][1][0];

    half8   A[2][4];
    float4v accA[4][2], accB[4][2];
    float4  bR[2];

    #pragma unroll 1
    for (int lp = 0; lp < 4; ++lp) {
        const int la = 2 * lp, lb = 2 * lp + 1;
        const _Float16* wla = Wall + la * (HDIM * HDIM) + lane * 8;
        const _Float16* wlb = Wall + lb * (HDIM * HDIM) + lane * 8;
        const float* bla = bK + la * HDIM;
        const float* blb = bK + lb * HDIM;
        const float* blp = bK + (la - 1) * HDIM;   // prev layer (lp>0 only)

        // ---- even layer: h0 -> h1 ----
        #pragma unroll
        for (int mt = 0; mt < 4; ++mt) {           // prologue: kt0, kt1
            A[0][mt] = *(const half8*)&wla[(mt * 8 + 0) * 512];
            A[1][mt] = *(const half8*)&wla[(mt * 8 + 1) * 512];
        }
        if (lp == 0)
            chunk_step<0, -1>(wla, bla, bla + qd4, bR,
                              lds1, laneM, quad, h0, h0, accA, accB, A);
        else
            chunk_step<0, 3>(wla, blp, bla + qd4, bR,
                             lds1, laneM, quad, h0, h0, accA, accB, A);
        chunk_step<1, 0>(wla, bla, bla + 64 + qd4, bR,
                         lds0, laneM, quad, h0, h1, accB, accA, A);
        chunk_step<2, 1>(wla, bla, bla + 128 + qd4, bR,
                         lds1, laneM, quad, h0, h1, accA, accB, A);
        chunk_step<3, 2>(wla, bla, bla + 192 + qd4, bR,
                         lds0, laneM, quad, h0, h1, accB, accA, A);

        // ---- odd layer: h1 -> h0 (chunk0 drains even layer's chunk3) ----
        #pragma unroll
        for (int mt = 0; mt < 4; ++mt) {
            A[0][mt] = *(const half8*)&wlb[(mt * 8 + 0) * 512];
            A[1][mt] = *(const half8*)&wlb[(mt * 8 + 1) * 512];
        }
        chunk_step<0, 3>(wlb, bla, blb + qd4, bR,
                         lds1, laneM, quad, h1, h1, accA, accB, A);
        chunk_step<1, 0>(wlb, blb, blb + 64 + qd4, bR,
                         lds0, laneM, quad, h1, h0, accB, accA, A);
        chunk_step<2, 1>(wlb, blb, blb + 128 + qd4, bR,
                         lds1, laneM, quad, h1, h0, accA, accB, A);
        chunk_step<3, 2>(wlb, blb, blb + 192 + qd4, bR,
                         lds0, laneM, quad, h1, h0, accB, accA, A);
    }
    // drain final layer's chunk 3 into h0[*][6],[7] (ring already primed)
    tail_epilogue(bK + 7 * HDIM, bR, lds1, laneM, quad, accB, h0);

    // -------- stage 3: output matvec from registers ------------------------
    {
        float s0 = 0.f, s1 = 0.f;
        #pragma unroll
        for (int kt = 0; kt < 8; ++kt) {
            const float4 wa = *(const float4*)&W_out[kt * 32 + quad * 8];
            const float4 wb = *(const float4*)&W_out[kt * 32 + quad * 8 + 4];
            s0 += dot8(h0[0][kt], wa, wb);
            s1 += dot8(h0[1][kt], wa, wb);
        }
        s0 += __shfl_xor(s0, 16); s0 += __shfl_xor(s0, 32);
        s1 += __shfl_xor(s1, 16); s1 += __shfl_xor(s1, 32);
        if (quad == 0) {
            const float bo = b_out[0];
            out[p0 + laneM]      = s0 + bo;
            out[p0 + 16 + laneM] = s1 + bo;
        }
    }
}

extern "C" void kernel_launch(void* const* d_in, const int* in_sizes, int n_in,
                              void* d_out, int out_size, void* d_ws, size_t ws_size,
                              hipStream_t stream) {
    const float* tx    = (const float*)d_in[0];
    const float* Bf    = (const float*)d_in[1];
    const float* W_in  = (const float*)d_in[2];
    const float* b_in  = (const float*)d_in[3];
    const float* W_h   = (const float*)d_in[4];
    const float* b_h   = (const float*)d_in[5];
    const float* W_out = (const float*)d_in[6];
    const float* b_out = (const float*)d_in[7];
    float* out = (float*)d_out;

    _Float16* Wall = (_Float16*)d_ws;   // 1 MiB weights + 8 KB bias table

    const int npts   = in_sizes[0] / 2;
    const int blocks = npts / TILE_N;   // 1024

    convert_w_kernel<<<WHALVES / NTHR, NTHR, 0, stream>>>(W_in, W_h, b_in, b_h, Wall);
    ffmlp_kernel<<<blocks, NTHR, 0, stream>>>(tx, Bf, Wall, W_out, b_out, out);
}

// Round 6
// 238.242 us; speedup vs baseline: 1.0399x; 1.0399x over previous
//
#include <hip/hip_runtime.h>

// FourierFeatureMLP fused kernel for MI355X (gfx950). Round 11.
//
// vs round 10 (207 us REGRESSION: +8-reg bias ring -> scratch spill,
// 90 MB/dispatch scratch traffic). Reverted. vs round 9 (184 us):
//  * VMEM-stream hygiene: per-slice bias float4 loads sat NEWEST in the
//    vmcnt queue -> waiting for bias drains the older A-prefetches too
//    (vmcnt is ordered) -> A-ring was effectively distance-0 at slice
//    kts. Fix: bias table (8 KB) staged to LDS once per block (one
//    barrier at kernel start); slices read it via ds_read (lgkm, does
//    NOT serialize vmcnt). K-loop VMEM = A-prefetch ONLY.
//  * 32x32x16 MFMA: same FLOPs at 8.45 cyc vs 2x4.85 -> matrix time
//    -13%; half the MFMA instructions; A-frags halve -> 3-slot
//    distance-2 ring at 24 VGPR (-8 vs round 9, off the spill cliff).
//  * 16-kt inner loop: tanh slices kt0-7, repack reads kt8-11, every kt
//    has non-MFMA cover for the A-load latency.
//
// Layouts (32x32x16, learn_hip m74/m101-verified):
//   A: lane holds A[m=lane&31][k=(lane>>5)*8+j]   (W fragment, half8)
//   B: lane holds B[k=(lane>>5)*8+j][n=lane&31]   (h fragment, n=point)
//   D: col(n)=lane&31, row(m)=(reg&3)+8*(reg>>2)+4*(lane>>5)
// Weights fragment-major: frag=((layer*4+c)*2+mm)*16+kt, 1 KB each,
// addr = frag*1024 + lane*16 -> fully-coalesced b128 loads.
// Repack LDS tile [32 rows(pts)][64 units], 16B-chunk XOR swizzle
// c8' = c8 ^ (row&7). Chunk CE produces next-layer h frags 4CE..4CE+3.

#define HDIM   256
#define NLAYER 8
#define PTSW   32
#define NTHR   256
#define TILE_N 128
#define WHALVES (NLAYER * HDIM * HDIM)

typedef __attribute__((ext_vector_type(8))) _Float16 half8;
typedef __attribute__((ext_vector_type(4))) _Float16 half4;
typedef __attribute__((ext_vector_type(2))) _Float16 half2;
typedef __attribute__((ext_vector_type(16))) float f32x16;

__device__ __forceinline__ half2 pk2(float a, float b) {
    return __builtin_bit_cast(half2, __builtin_amdgcn_cvt_pkrtz(a, b));
}

// tanh(acc + b) with pre-scaled bias bK = b * 2/ln2:
// t = acc*K + bK; z = 2^t; r = 1/(1+z); tanh = 1 - 2r. Saturation-safe.
#define TANH_K 2.885390081777927f
__device__ __forceinline__ float fast_tanh_fused(float acc, float bK) {
    float z = __builtin_amdgcn_exp2f(fmaf(acc, TANH_K, bK));
    float r = __builtin_amdgcn_rcpf(z + 1.0f);
    return fmaf(-2.0f, r, 1.0f);
}

__device__ __forceinline__ f32x16 zero16() {
    f32x16 v;
    #pragma unroll
    for (int i = 0; i < 16; ++i) v[i] = 0.f;
    return v;
}

// ---- pre-pass: fp32 -> fp16 weights, FRAGMENT-major for 32x32x16,
// plus pre-scaled f32 bias table bK[layer*256+u] at halfs offset WHALVES.
__global__ void convert_w_kernel(const float* __restrict__ W_in,
                                 const float* __restrict__ W_h,
                                 const float* __restrict__ b_in,
                                 const float* __restrict__ b_h,
                                 _Float16* __restrict__ dst)
{
    const int i = blockIdx.x * blockDim.x + threadIdx.x;   // 0 .. WHALVES-1
    const int j     = i & 7;
    const int lane  = (i >> 3) & 63;
    const int frag  = i >> 9;
    const int kt    = frag & 15;
    const int mm    = (frag >> 4) & 1;
    const int c     = (frag >> 5) & 3;
    const int layer = frag >> 7;
    const int u = c * 64 + mm * 32 + (lane & 31);
    const int k = kt * 16 + (lane >> 5) * 8 + j;
    const float v = (layer == 0) ? W_in[u * HDIM + k]
                                 : W_h[((layer - 1) * HDIM + u) * HDIM + k];
    dst[i] = (_Float16)v;

    if (i < NLAYER * HDIM) {                               // bias table
        float* bk = (float*)(dst + WHALVES);
        const int l = i >> 8, uu = i & 255;
        const float b = (l == 0) ? b_in[uu] : b_h[(l - 1) * HDIM + uu];
        bk[i] = b * TANH_K;
    }
}

// One chunk (64 units, full K=256) = 16 kt x 2 MFMA, with the PREVIOUS
// chunk's (CE) epilogue interleaved: tanh slices kt0-7 (bias from LDS),
// repack ds_reads kt8-11. A-ring: slot (C+kt)%3, distance-2 prefetch.
// CE==-1: no epilogue (first chunk of layer 0).
template<int C, int CE>
__device__ __forceinline__ void chunk_step(const _Float16* __restrict__ wl,
                                           const float* __restrict__ bE,  // LDS bias base for CE
                                           _Float16* __restrict__ lds,    // wave-private 2048 halfs
                                           const int row, const int hi,
                                           const half8 (&hin)[16],
                                           half8 (&hdst)[16],
                                           f32x16 (&acc)[2],
                                           f32x16 (&accP)[2],
                                           half8 (&A)[3][2])
{
    acc[0] = zero16();
    acc[1] = zero16();

    #pragma unroll
    for (int kt = 0; kt < 16; ++kt) {
        const int idx = C * 16 + kt;
        // distance-2 weight prefetch (VMEM stream = A-loads ONLY)
        if (idx + 2 < 64) {
            const int c2 = (idx + 2) >> 4, k2 = (idx + 2) & 15;
            const int ws = (C + kt + 2) % 3;
            A[ws][0] = *(const half8*)&wl[c2 * 16384 + k2 * 512];
            A[ws][1] = *(const half8*)&wl[c2 * 16384 + 8192 + k2 * 512];
        }

        // ---- epilogue work for chunk CE, before this kt's MFMAs ----
        if constexpr (CE >= 0) {
            if (kt < 8) {                       // tanh slice s=kt: mm, r-group g
                const int mm = kt >> 2, g = kt & 3;
                const float4 b4 = *(const float4*)&bE[mm * 32 + g * 8 + hi * 4];
                const float v0 = fast_tanh_fused(accP[mm][4 * g + 0], b4.x);
                const float v1 = fast_tanh_fused(accP[mm][4 * g + 1], b4.y);
                const float v2 = fast_tanh_fused(accP[mm][4 * g + 2], b4.z);
                const float v3 = fast_tanh_fused(accP[mm][4 * g + 3], b4.w);
                const half2 lo = pk2(v0, v1);
                const half2 h2 = pk2(v2, v3);
                half4 pkv;
                pkv.x = lo.x; pkv.y = lo.y; pkv.z = h2.x; pkv.w = h2.y;
                const int c8 = 4 * mm + g;      // units c8*8+4*hi .. +3
                *(half4*)&lds[row * 64 + ((c8 ^ (row & 7)) << 3) + hi * 4] = pkv;
            } else if (kt < 12) {               // repack reads q = kt-8
                const int q = kt - 8;
                const int c8r = (2 * q + hi) ^ (row & 7);
                hdst[CE * 4 + q] = *(const half8*)&lds[row * 64 + (c8r << 3)];
            }
        }

        const int slot = (C + kt) % 3;
        acc[0] = __builtin_amdgcn_mfma_f32_32x32x16_f16(A[slot][0], hin[kt], acc[0], 0, 0, 0);
        acc[1] = __builtin_amdgcn_mfma_f32_32x32x16_f16(A[slot][1], hin[kt], acc[1], 0, 0, 0);
    }
}

// Standalone drain of the final layer's chunk 3 -> h frags 12..15.
__device__ __forceinline__ void tail_epilogue(const float* __restrict__ bE,
                                              _Float16* __restrict__ lds,
                                              const int row, const int hi,
                                              f32x16 (&accP)[2],
                                              half8 (&hdst)[16])
{
    #pragma unroll
    for (int s = 0; s < 8; ++s) {
        const int mm = s >> 2, g = s & 3;
        const float4 b4 = *(const float4*)&bE[mm * 32 + g * 8 + hi * 4];
        const float v0 = fast_tanh_fused(accP[mm][4 * g + 0], b4.x);
        const float v1 = fast_tanh_fused(accP[mm][4 * g + 1], b4.y);
        const float v2 = fast_tanh_fused(accP[mm][4 * g + 2], b4.z);
        const float v3 = fast_tanh_fused(accP[mm][4 * g + 3], b4.w);
        const half2 lo = pk2(v0, v1);
        const half2 h2 = pk2(v2, v3);
        half4 pkv;
        pkv.x = lo.x; pkv.y = lo.y; pkv.z = h2.x; pkv.w = h2.y;
        const int c8 = 4 * mm + g;
        *(half4*)&lds[row * 64 + ((c8 ^ (row & 7)) << 3) + hi * 4] = pkv;
    }
    #pragma unroll
    for (int q = 0; q < 4; ++q) {
        const int c8r = (2 * q + hi) ^ (row & 7);
        hdst[12 + q] = *(const half8*)&lds[row * 64 + (c8r << 3)];
    }
}

__device__ __forceinline__ float dot8(const half8 h, const float4 wa, const float4 wb) {
    return (float)h[0]*wa.x + (float)h[1]*wa.y + (float)h[2]*wa.z + (float)h[3]*wa.w
         + (float)h[4]*wb.x + (float)h[5]*wb.y + (float)h[6]*wb.z + (float)h[7]*wb.w;
}

__global__ __launch_bounds__(NTHR, 2)
void ffmlp_kernel(const float* __restrict__ tx,
                  const float* __restrict__ Bf,
                  const _Float16* __restrict__ Wall,
                  const float* __restrict__ W_out,
                  const float* __restrict__ b_out,
                  float* __restrict__ out)
{
    __shared__ __align__(16) _Float16 lbuf[4][2048];      // 16 KB repack (4 KB/wave)
    __shared__ __align__(16) float    blds[NLAYER * HDIM]; // 8 KB bias

    const int tid  = threadIdx.x;
    const int wave = tid >> 6;
    const int lane = tid & 63;
    const int row  = lane & 31;          // point within wave tile
    const int hi   = lane >> 5;          // k-half
    const int p0   = blockIdx.x * TILE_N + wave * PTSW;

    // -------- stage 0: bias table -> LDS (once; the only barrier) --------
    {
        const float4* s4 = (const float4*)((const float*)(Wall + WHALVES));
        float4* d4 = (float4*)blds;
        d4[tid]       = s4[tid];
        d4[tid + 256] = s4[tid + 256];
    }
    __syncthreads();

    half8 h0[16], h1[16];

    // -------- stage 1: Fourier features directly into B-frag registers ----
    // frag kq holds k = kq*16 + hi*8 + j; kq<8 -> sin(f=k), kq>=8 -> cos.
    // sin(2*pi*r) = v_sin(fract(r)) : argument in revolutions.
    {
        const float2* txv = (const float2*)tx;
        const float2* Bv  = (const float2*)Bf;
        const float2 t = txv[p0 + row];
        #pragma unroll
        for (int kq = 0; kq < 8; ++kq) {
            const int f0 = kq * 16 + hi * 8;
            half8 s8, c8v;
            #pragma unroll
            for (int jj = 0; jj < 8; jj += 2) {
                const float2 bA = Bv[f0 + jj];
                const float2 bB = Bv[f0 + jj + 1];
                const float r0 = __builtin_amdgcn_fractf(t.x * bA.x + t.y * bA.y);
                const float r1 = __builtin_amdgcn_fractf(t.x * bB.x + t.y * bB.y);
                const half2 sp = pk2(__builtin_amdgcn_sinf(r0), __builtin_amdgcn_sinf(r1));
                const half2 cp = pk2(__builtin_amdgcn_cosf(r0), __builtin_amdgcn_cosf(r1));
                s8[jj] = sp.x;  s8[jj + 1] = sp.y;
                c8v[jj] = cp.x; c8v[jj + 1] = cp.y;
            }
            h0[kq]     = s8;
            h0[kq + 8] = c8v;
        }
    }

    // -------- stage 2: 8 dense layers, wave-local, no barriers,
    //          prev-chunk epilogue pipelined into current chunk's K-loop --
    _Float16* __restrict__ lds = &lbuf[wave][0];
    const float* bls = blds;

    half8  A[3][2];
    f32x16 accA[2], accB[2];

    #pragma unroll 1
    for (int lp = 0; lp < 4; ++lp) {
        const int la = 2 * lp, lb = 2 * lp + 1;
        const _Float16* wla = Wall + la * (HDIM * HDIM) + lane * 8;
        const _Float16* wlb = Wall + lb * (HDIM * HDIM) + lane * 8;

        // ---- even layer: h0 -> h1 ---- (prologue: idx 0,1 -> slots 0,1)
        A[0][0] = *(const half8*)&wla[0];
        A[0][1] = *(const half8*)&wla[8192];
        A[1][0] = *(const half8*)&wla[512];
        A[1][1] = *(const half8*)&wla[8192 + 512];

        if (lp == 0)
            chunk_step<0, -1>(wla, bls, lds, row, hi, h0, h0, accA, accB, A);
        else
            chunk_step<0, 3>(wla, bls + (la - 1) * 256 + 192, lds, row, hi,
                             h0, h0, accA, accB, A);
        chunk_step<1, 0>(wla, bls + la * 256 +   0, lds, row, hi, h0, h1, accB, accA, A);
        chunk_step<2, 1>(wla, bls + la * 256 +  64, lds, row, hi, h0, h1, accA, accB, A);
        chunk_step<3, 2>(wla, bls + la * 256 + 128, lds, row, hi, h0, h1, accB, accA, A);

        // ---- odd layer: h1 -> h0 (chunk0 drains even layer's chunk3) ----
        A[0][0] = *(const half8*)&wlb[0];
        A[0][1] = *(const half8*)&wlb[8192];
        A[1][0] = *(const half8*)&wlb[512];
        A[1][1] = *(const half8*)&wlb[8192 + 512];

        chunk_step<0, 3>(wlb, bls + la * 256 + 192, lds, row, hi, h1, h1, accA, accB, A);
        chunk_step<1, 0>(wlb, bls + lb * 256 +   0, lds, row, hi, h1, h0, accB, accA, A);
        chunk_step<2, 1>(wlb, bls + lb * 256 +  64, lds, row, hi, h1, h0, accA, accB, A);
        chunk_step<3, 2>(wlb, bls + lb * 256 + 128, lds, row, hi, h1, h0, accB, accA, A);
    }
    // drain final layer's chunk 3 into h0 frags 12..15
    tail_epilogue(bls + 7 * 256 + 192, lds, row, hi, accB, h0);

    // -------- stage 3: output matvec from registers ------------------------
    {
        float s = 0.f;
        #pragma unroll
        for (int kq = 0; kq < 16; ++kq) {
            const float4 wa = *(const float4*)&W_out[kq * 16 + hi * 8];
            const float4 wb = *(const float4*)&W_out[kq * 16 + hi * 8 + 4];
            s += dot8(h0[kq], wa, wb);
        }
        s += __shfl_xor(s, 32);              // combine the two k-halves
        if (hi == 0)
            out[p0 + row] = s + b_out[0];
    }
}

extern "C" void kernel_launch(void* const* d_in, const int* in_sizes, int n_in,
                              void* d_out, int out_size, void* d_ws, size_t ws_size,
                              hipStream_t stream) {
    const float* tx    = (const float*)d_in[0];
    const float* Bf    = (const float*)d_in[1];
    const float* W_in  = (const float*)d_in[2];
    const float* b_in  = (const float*)d_in[3];
    const float* W_h   = (const float*)d_in[4];
    const float* b_h   = (const float*)d_in[5];
    const float* W_out = (const float*)d_in[6];
    const float* b_out = (const float*)d_in[7];
    float* out = (float*)d_out;

    _Float16* Wall = (_Float16*)d_ws;   // 1 MiB weights + 8 KB bias table

    const int npts   = in_sizes[0] / 2;
    const int blocks = npts / TILE_N;   // 1024

    convert_w_kernel<<<WHALVES / NTHR, NTHR, 0, stream>>>(W_in, W_h, b_in, b_h, Wall);
    ffmlp_kernel<<<blocks, NTHR, 0, stream>>>(tx, Bf, Wall, W_out, b_out, out);
}